// Round 1
// baseline (1245.546 us; speedup 1.0000x reference)
//
#include <hip/hip_runtime.h>

// MQIF neuron scan.
// input_current: [16, 4096, 512] f32
// outputs (concat in d_out): v_trace [16, 4097, 512] f32, spikes [16, 4097, 512] f32 (0/1)
//
// Parallelism = 8192 independent (batch, feature) sequences; recurrence over t is serial.
// Round 1: one thread per sequence, 128 blocks x 64 threads, register double-buffer
// prefetch of U=16 input steps to hide HBM latency.

#define STEPS 4096
#define FEATS 512
#define BATCH 16

__global__ __launch_bounds__(64) void mqif_kernel(const float* __restrict__ in,
                                                  float* __restrict__ vtr,
                                                  float* __restrict__ spk) {
    // Constants (match reference):
    // a=0.04 b=0.2 vr=-60 vt=-40 v_reset=-60 v_peak=30 d=2 tau_m=10 tau_u=100 dt=0.05
    constexpr float VR_     = -60.0f;
    constexpr float VT_     = -40.0f;
    constexpr float VRESET_ = -60.0f;
    constexpr float VPEAK_  = 30.0f;
    constexpr float D_      = 2.0f;
    constexpr float A_      = 0.04f;
    constexpr float B_      = 0.2f;
    constexpr float DT_TM   = 0.005f;   // dt / tau_m
    constexpr float DT_TU   = 0.0005f;  // dt / tau_u

    const int gid = blockIdx.x;            // 0..127
    const int b   = gid >> 3;              // 16 batches
    const int f   = ((gid & 7) << 6) + threadIdx.x;  // 8 chunks of 64 features

    const float* ip = in  + (size_t)b * STEPS * FEATS + f;
    float*       vp = vtr + (size_t)b * (STEPS + 1) * FEATS + f;
    float*       sp = spk + (size_t)b * (STEPS + 1) * FEATS + f;

    constexpr int U = 16;                  // prefetch depth (time steps)
    float buf[2][U];

    float v = VR_;   // v_init defaults to vr
    float u = 0.0f;  // u_init defaults to 0

    #pragma unroll
    for (int j = 0; j < U; ++j) buf[0][j] = ip[(size_t)j * FEATS];

    constexpr int NCH = STEPS / U;
    for (int c = 0; c < NCH; ++c) {
        const int cur = c & 1;
        const int nxt = cur ^ 1;
        if (c + 1 < NCH) {
            const float* ipn = ip + (size_t)(c + 1) * U * FEATS;
            #pragma unroll
            for (int j = 0; j < U; ++j) buf[nxt][j] = ipn[(size_t)j * FEATS];
        }
        const int t0 = c * U;
        #pragma unroll
        for (int j = 0; j < U; ++j) {
            const float it    = buf[cur][j];
            const bool  fired = (v >= VPEAK_);
            const float vvis  = fired ? VPEAK_ : v;

            const float t1    = v - VR_;                    // v - vr
            const float quad  = A_ * t1 * (v - VT_);        // a*(v-vr)*(v-vt)
            const float vn_nf = v + DT_TM * (quad - u + it);
            const float un_nf = u + DT_TU * (B_ * t1 - u);

            const float vn = fired ? VRESET_ : vn_nf;
            const float un = fired ? (u + D_) : un_nf;

            vp[(size_t)(t0 + j) * FEATS] = vvis;
            sp[(size_t)(t0 + j) * FEATS] = fired ? 1.0f : 0.0f;

            v = vn;
            u = un;
        }
    }

    // Row STEPS: raw final voltage, and spike test on it.
    vp[(size_t)STEPS * FEATS] = v;
    sp[(size_t)STEPS * FEATS] = (v >= VPEAK_) ? 1.0f : 0.0f;
}

extern "C" void kernel_launch(void* const* d_in, const int* in_sizes, int n_in,
                              void* d_out, int out_size, void* d_ws, size_t ws_size,
                              hipStream_t stream) {
    const float* in = (const float*)d_in[0];
    float* vtr = (float*)d_out;
    float* spk = (float*)d_out + (size_t)BATCH * (STEPS + 1) * FEATS;

    dim3 grid(BATCH * (FEATS / 64));  // 128 blocks
    dim3 block(64);
    mqif_kernel<<<grid, block, 0, stream>>>(in, vtr, spk);
}

// Round 2
// 550.682 us; speedup vs baseline: 2.2618x; 2.2618x over previous
//
#include <hip/hip_runtime.h>

// MQIF neuron scan.
// input_current: [16, 4096, 512] f32
// outputs (concat in d_out): v_trace [16, 4097, 512] f32, spikes [16, 4097, 512] f32 (0/1)
//
// Round 2:
//  - 256 blocks x 64 threads, only lanes 0..31 active -> 32 sequences per CU,
//    all 256 CUs streaming (round 1 used 128 CUs).
//  - Register double-buffer with STATIC indexing (bufA/bufB, chunk pairs
//    unrolled) so the prefetch provably lives in VGPRs. Round 1's buf[cur][j]
//    runtime indexing collapsed to load-on-demand (VGPR_Count=36, 992 us,
//    338 GB/s -> latency-bound).
//  - U=64 steps prefetched per buffer: 64 independent loads in flight while
//    computing the previous 64 steps (compute window ~1536 cyc > ~900 cyc
//    HBM latency).
//  - Nontemporal stores for the write-once 268 MB output.

#define STEPS 4096
#define FEATS 512
#define BATCH 16
#define UU 64                 // prefetch depth (time steps per buffer)
#define NCH (STEPS / UU)      // 64 chunks (even, so chunk-pair loop is exact)

__global__ __launch_bounds__(64, 1) void mqif_kernel(const float* __restrict__ in,
                                                     float* __restrict__ vtr,
                                                     float* __restrict__ spk) {
    // a=0.04 b=0.2 vr=-60 vt=-40 v_reset=-60 v_peak=30 d=2 tau_m=10 tau_u=100 dt=0.05
    constexpr float VR_     = -60.0f;
    constexpr float VT_     = -40.0f;
    constexpr float VRESET_ = -60.0f;
    constexpr float VPEAK_  = 30.0f;
    constexpr float D_      = 2.0f;
    constexpr float A_      = 0.04f;
    constexpr float B_      = 0.2f;
    constexpr float DT_TM   = 0.005f;   // dt / tau_m
    constexpr float DT_TU   = 0.0005f;  // dt / tau_u

    const int lane = threadIdx.x;
    if (lane >= 32) return;            // 32 sequences per block -> 256 blocks cover 8192

    const int bid = blockIdx.x;        // 0..255
    const int b   = bid >> 4;          // 16 batches
    const int f   = ((bid & 15) << 5) + lane;  // 16 chunks of 32 features

    const float* ip = in  + (size_t)b * STEPS * FEATS + f;
    float*       vp = vtr + (size_t)b * (STEPS + 1) * FEATS + f;
    float*       sp = spk + (size_t)b * (STEPS + 1) * FEATS + f;

    float bufA[UU], bufB[UU];
    float v = VR_;   // v_init defaults to vr
    float u = 0.0f;  // u_init defaults to 0

    // Prime chunk 0 into bufA.
    #pragma unroll
    for (int j = 0; j < UU; ++j) bufA[j] = ip[(size_t)j * FEATS];

    // Process UU steps from a register buffer; all indices compile-time.
    auto process = [&](const float (&buf)[UU], int t0) {
        #pragma unroll
        for (int j = 0; j < UU; ++j) {
            const float it    = buf[j];
            const bool  fired = (v >= VPEAK_);
            const float vvis  = fired ? VPEAK_ : v;

            const float t1    = v - VR_;                    // v - vr
            const float quad  = A_ * t1 * (v - VT_);        // a*(v-vr)*(v-vt)
            const float vn_nf = v + DT_TM * (quad - u + it);
            const float un_nf = u + DT_TU * (B_ * t1 - u);

            __builtin_nontemporal_store(vvis, &vp[(size_t)(t0 + j) * FEATS]);
            __builtin_nontemporal_store(fired ? 1.0f : 0.0f, &sp[(size_t)(t0 + j) * FEATS]);

            v = fired ? VRESET_ : vn_nf;
            u = fired ? (u + D_) : un_nf;
        }
    };

    for (int c = 0; c < NCH; c += 2) {
        // Load chunk c+1 into bufB while computing chunk c from bufA.
        {
            const float* q = ip + (size_t)(c + 1) * UU * FEATS;
            #pragma unroll
            for (int j = 0; j < UU; ++j) bufB[j] = q[(size_t)j * FEATS];
        }
        process(bufA, c * UU);

        // Load chunk c+2 into bufA while computing chunk c+1 from bufB.
        if (c + 2 < NCH) {
            const float* q = ip + (size_t)(c + 2) * UU * FEATS;
            #pragma unroll
            for (int j = 0; j < UU; ++j) bufA[j] = q[(size_t)j * FEATS];
        }
        process(bufB, (c + 1) * UU);
    }

    // Row STEPS: raw final voltage, and spike test on it.
    __builtin_nontemporal_store(v, &vp[(size_t)STEPS * FEATS]);
    __builtin_nontemporal_store((v >= VPEAK_) ? 1.0f : 0.0f, &sp[(size_t)STEPS * FEATS]);
}

extern "C" void kernel_launch(void* const* d_in, const int* in_sizes, int n_in,
                              void* d_out, int out_size, void* d_ws, size_t ws_size,
                              hipStream_t stream) {
    const float* in = (const float*)d_in[0];
    float* vtr = (float*)d_out;
    float* spk = (float*)d_out + (size_t)BATCH * (STEPS + 1) * FEATS;

    dim3 grid(256);
    dim3 block(64);
    mqif_kernel<<<grid, block, 0, stream>>>(in, vtr, spk);
}

// Round 3
// 458.544 us; speedup vs baseline: 2.7163x; 1.2009x over previous
//
#include <hip/hip_runtime.h>

// MQIF neuron scan. input [16,4096,512] f32 -> v_trace [16,4097,512], spikes [16,4097,512] (concat).
//
// Round 3: producer-consumer through LDS.
//  R2 failure: compiler clamped in-flight register prefetch (VGPR=84 << 128 needed)
//  -> 1.1 TB/s latency ceiling. Fix: wave 1 streams input via global_load_lds DMA
//  (16 B/lane, 1024 B/instr) into a double-buffered LDS ring; wave 0 (32 active
//  lanes = 32 sequences) runs the serial scan from LDS and stores directly.
//  One __syncthreads per 128-step chunk; the compiler's vmcnt(0)-before-barrier
//  is the producer's publication of the next chunk.

#define STEPS 4096
#define FEATS 512
#define BATCH 16
#define CHNK  128              // steps per chunk
#define NCH   (STEPS / CHNK)   // 32
#define SEQ   32               // sequences (features) per block

typedef __attribute__((address_space(3))) void lds_void;
typedef __attribute__((address_space(1))) void g_void;

__global__ __launch_bounds__(128, 1)
void mqif_kernel(const float* __restrict__ in,
                 float* __restrict__ vtr,
                 float* __restrict__ spk) {
    // a=0.04 b=0.2 vr=-60 vt=-40 v_reset=-60 v_peak=30 d=2 tau_m=10 tau_u=100 dt=0.05
    constexpr float VPEAK_  = 30.0f;
    constexpr float VRESET_ = -60.0f;
    constexpr float D_      = 2.0f;
    // v_next = v + 0.005*(0.04*(v+60)*(v+40) - u + i)
    //        = (C2*v + C1)*v + (C0 + 0.005*(i - u))
    constexpr float C2 = 2.0e-4f;        // 0.005*0.04
    constexpr float C1 = 1.02f;          // 1 + 0.005*0.04*100
    constexpr float C0 = 0.48f;          // 0.005*0.04*2400
    constexpr float DT_TM = 0.005f;
    // u_next = u + 0.0005*(0.2*(v+60) - u) = KU*u + (KB*v + KBV)
    constexpr float KU  = 1.0f - 5.0e-4f;
    constexpr float KB  = 1.0e-4f;
    constexpr float KBV = 6.0e-3f;

    __shared__ float lds[2][CHNK * SEQ];   // 2 x 16 KB

    const int tid  = threadIdx.x;
    const int wid  = tid >> 6;
    const int lane = tid & 63;
    const int bid  = blockIdx.x;           // 0..255
    const int b    = bid >> 4;             // 16 batches
    const int fb   = (bid & 15) << 5;      // 16 chunks of 32 features

    const float* gin = in + (size_t)b * STEPS * FEATS + fb;

    if (wid == 1) {
        // ---- producer wave ----
        // per global_load_lds instr: 64 lanes x 16 B = 1024 B = 8 step-rows of 128 B
        const int r  = lane >> 3;          // 0..7   step-row within the 8-row group
        const int cb = (lane & 7) << 2;    // 0,4,..28  feature offset (floats)
        for (int c = 0; c <= NCH; ++c) {
            if (c < NCH) {
                float* dst = &lds[c & 1][0];
                const float* src = gin + (size_t)c * CHNK * FEATS;
                #pragma unroll
                for (int k = 0; k < (CHNK * SEQ) / 256; ++k) {   // 16 instrs
                    const float* s = src + (size_t)(k * 8 + r) * FEATS + cb;
                    __builtin_amdgcn_global_load_lds((const g_void*)s,
                                                     (lds_void*)(dst + k * 256),
                                                     16, 0, 0);
                }
            }
            __syncthreads();
        }
        return;
    }

    // ---- consumer wave ----
    if (lane >= SEQ) {
        // dead lanes still must not skip barriers? s_barrier is wave-granular,
        // wave 0 remains resident via lanes 0..31 -> safe to exit.
        return;
    }

    float* vp = vtr + (size_t)b * (STEPS + 1) * FEATS + fb + lane;
    float* sp = spk + (size_t)b * (STEPS + 1) * FEATS + fb + lane;

    float v = -60.0f;   // v_init = vr
    float u = 0.0f;

    for (int c = 0; c <= NCH; ++c) {
        if (c >= 1) {
            const float* buf = &lds[(c - 1) & 1][lane];
            const int t0 = (c - 1) * CHNK;
            #pragma unroll 16
            for (int j = 0; j < CHNK; ++j) {
                const float it   = buf[(size_t)j * SEQ];          // conflict-free: bank=lane
                const bool fired = (v >= VPEAK_);
                const float vvis = fminf(v, VPEAK_);              // == fired?VPEAK:v
                const float sval = fired ? 1.0f : 0.0f;

                const float w  = fmaf(DT_TM, it - u, C0);
                const float p  = fmaf(C2, v, C1);
                const float vn = fmaf(p, v, w);
                const float un = fmaf(KU, u, fmaf(KB, v, KBV));

                __builtin_nontemporal_store(vvis, vp + (size_t)(t0 + j) * FEATS);
                __builtin_nontemporal_store(sval, sp + (size_t)(t0 + j) * FEATS);

                v = fired ? VRESET_ : vn;
                u = fired ? (u + D_) : un;
            }
        }
        __syncthreads();
    }

    // Row STEPS: raw final voltage + spike test on it.
    __builtin_nontemporal_store(v, vp + (size_t)STEPS * FEATS);
    __builtin_nontemporal_store((v >= VPEAK_) ? 1.0f : 0.0f, sp + (size_t)STEPS * FEATS);
}

extern "C" void kernel_launch(void* const* d_in, const int* in_sizes, int n_in,
                              void* d_out, int out_size, void* d_ws, size_t ws_size,
                              hipStream_t stream) {
    const float* in = (const float*)d_in[0];
    float* vtr = (float*)d_out;
    float* spk = (float*)d_out + (size_t)BATCH * (STEPS + 1) * FEATS;

    dim3 grid(256);
    dim3 block(128);
    mqif_kernel<<<grid, block, 0, stream>>>(in, vtr, spk);
}

// Round 5
// 402.017 us; speedup vs baseline: 3.0982x; 1.1406x over previous
//
#include <hip/hip_runtime.h>

// MQIF neuron scan. input [16,4096,512] f32 -> v_trace [16,4097,512], spikes [16,4097,512] (concat).
//
// Round 5 (= Round 4 with compile fix: native vector type for nontemporal store).
//  R3 diagnosis: consumer ran ~120 cyc/step (issue cost only ~30) with VALUBusy 11%
//  -> the 2 nontemporal global stores per step stalled the scan on vmcnt (store data
//  VGPR recycling waits for HBM completion ~900 cyc). Fix: 4-wave pipeline.
//    wave 0: consumer  - scan from LDS, results to LDS (ds ops only, no VMEM)
//    wave 1: producer  - global_load_lds DMA of input chunks (as R3)
//    wave 2: writer-v  - LDS -> global dwordx4 nt stores (1 KB/instr)
//    wave 3: writer-s  - same for spikes
//  3-deep chunk pipeline, one __syncthreads per stage.

#define STEPS 4096
#define FEATS 512
#define BATCH 16
#define CHNK  128              // steps per chunk
#define NCH   (STEPS / CHNK)   // 32
#define SEQ   32               // sequences (features) per block

typedef __attribute__((address_space(3))) void lds_void;
typedef __attribute__((address_space(1))) void g_void;
typedef float v4f __attribute__((ext_vector_type(4)));

__global__ __launch_bounds__(256, 1)
void mqif_kernel(const float* __restrict__ in,
                 float* __restrict__ vtr,
                 float* __restrict__ spk) {
    // a=0.04 b=0.2 vr=-60 vt=-40 v_reset=-60 v_peak=30 d=2 tau_m=10 tau_u=100 dt=0.05
    constexpr float VPEAK_  = 30.0f;
    constexpr float VRESET_ = -60.0f;
    constexpr float D_      = 2.0f;
    // v_next = v + 0.005*(0.04*(v+60)*(v+40) - u + i) = (C2*v + C1)*v + C0 + 0.005*i - 0.005*u
    constexpr float C2 = 2.0e-4f;        // 0.005*0.04
    constexpr float C1 = 1.02f;          // 1 + 0.005*0.04*100
    constexpr float C0 = 0.48f;          // 0.005*0.04*2400
    constexpr float DT_TM = 0.005f;
    // u_next = u + 0.0005*(0.2*(v+60) - u) = KU*u + KB*v + KBV
    constexpr float KU  = 1.0f - 5.0e-4f;
    constexpr float KB  = 1.0e-4f;
    constexpr float KBV = 6.0e-3f;

    __shared__ __align__(16) float Lin[2][CHNK * SEQ];   // input chunks   (2 x 16 KB)
    __shared__ __align__(16) float Lv [2][CHNK * SEQ];   // vvis results   (2 x 16 KB)
    __shared__ __align__(16) float Ls [2][CHNK * SEQ];   // spike results  (2 x 16 KB)

    const int tid  = threadIdx.x;
    const int wid  = tid >> 6;
    const int lane = tid & 63;
    const int bid  = blockIdx.x;           // 0..255
    const int b    = bid >> 4;             // 16 batches
    const int fb   = (bid & 15) << 5;      // 16 chunks of 32 features

    const float* gin = in  + (size_t)b * STEPS * FEATS + fb;
    float*       gv  = vtr + (size_t)b * (STEPS + 1) * FEATS + fb;
    float*       gs  = spk + (size_t)b * (STEPS + 1) * FEATS + fb;

    // lane decomposition for 1 KB-per-instruction row groups (8 rows x 128 B)
    const int r  = lane >> 3;              // 0..7  step-row within group
    const int cb = (lane & 7) << 2;        // 0,4,..,28 float offset

    float v = -60.0f;   // v_init = vr
    float u = 0.0f;

    for (int c = 0; c <= NCH + 1; ++c) {
        if (wid == 1) {
            // ---- producer: load input chunk c into Lin[c&1] ----
            if (c < NCH) {
                float* dst = &Lin[c & 1][0];
                const float* src = gin + (size_t)c * CHNK * FEATS;
                #pragma unroll
                for (int k = 0; k < 16; ++k) {           // 16 x 1024 B
                    const float* s = src + (size_t)(k * 8 + r) * FEATS + cb;
                    __builtin_amdgcn_global_load_lds((const g_void*)s,
                                                     (lds_void*)(dst + k * 256),
                                                     16, 0, 0);
                }
            }
        } else if (wid == 0) {
            // ---- consumer: scan chunk c-1 (LDS in, LDS out; NO VMEM) ----
            if (c >= 1 && c <= NCH && lane < SEQ) {
                const int bi = (c - 1) & 1;
                const float* bin = &Lin[bi][lane];
                float*       bv  = &Lv [bi][lane];
                float*       bs  = &Ls [bi][lane];

                float cur[16], nxt[16];
                #pragma unroll
                for (int j = 0; j < 16; ++j) cur[j] = bin[j * SEQ];

                #pragma unroll
                for (int g = 0; g < 8; ++g) {            // 8 groups of 16 steps
                    if (g < 7) {
                        #pragma unroll
                        for (int j = 0; j < 16; ++j)
                            nxt[j] = bin[(g * 16 + 16 + j) * SEQ];
                    }
                    #pragma unroll
                    for (int j = 0; j < 16; ++j) {
                        const float it    = cur[j];
                        const bool  fired = (v >= VPEAK_);
                        const float vvis  = fminf(v, VPEAK_);
                        const float sval  = fired ? 1.0f : 0.0f;

                        const float w0 = __builtin_fmaf(-DT_TM, u, C0);
                        const float w  = __builtin_fmaf(DT_TM, it, w0);
                        const float p  = __builtin_fmaf(C2, v, C1);
                        const float vn = __builtin_fmaf(p, v, w);
                        const float t  = __builtin_fmaf(KB, v, KBV);
                        const float un = __builtin_fmaf(KU, u, t);

                        bv[(g * 16 + j) * SEQ] = vvis;
                        bs[(g * 16 + j) * SEQ] = sval;

                        v = fired ? VRESET_ : vn;
                        u = fired ? (u + D_) : un;
                    }
                    #pragma unroll
                    for (int j = 0; j < 16; ++j) cur[j] = nxt[j];
                }
            }
        } else {
            // ---- writers: drain result chunk c-2 from LDS to global ----
            if (c >= 2) {
                const int c2 = c - 2;
                const int bi = c & 1;                    // (c-2)&1 == c&1
                const float* lsrc = (wid == 2) ? &Lv[bi][0] : &Ls[bi][0];
                float* gdst = ((wid == 2) ? gv : gs) + (size_t)c2 * CHNK * FEATS;
                #pragma unroll
                for (int k = 0; k < 16; ++k) {           // 16 x 1024 B nt stores
                    const int row = k * 8 + r;
                    const v4f val = *(const v4f*)&lsrc[(size_t)row * SEQ + cb];
                    __builtin_nontemporal_store(val, (v4f*)(gdst + (size_t)row * FEATS + cb));
                }
            }
        }
        __syncthreads();
    }

    // Row STEPS: raw final voltage + spike test on it (tiny, after last barrier).
    if (wid == 0 && lane < SEQ) {
        gv[(size_t)STEPS * FEATS + lane] = v;
        gs[(size_t)STEPS * FEATS + lane] = (v >= VPEAK_) ? 1.0f : 0.0f;
    }
}

extern "C" void kernel_launch(void* const* d_in, const int* in_sizes, int n_in,
                              void* d_out, int out_size, void* d_ws, size_t ws_size,
                              hipStream_t stream) {
    const float* in = (const float*)d_in[0];
    float* vtr = (float*)d_out;
    float* spk = (float*)d_out + (size_t)BATCH * (STEPS + 1) * FEATS;

    dim3 grid(256);
    dim3 block(256);
    mqif_kernel<<<grid, block, 0, stream>>>(in, vtr, spk);
}